// Round 16
// baseline (102.733 us; speedup 1.0000x reference)
//
#include <hip/hip_runtime.h>

#define H 512
#define W 512
#define HW (H * W)
#define T 128
#define DECAY 0.8f
#define TC 16               // planes per chunk
#define NCHUNK (T / TC)     // 8

typedef float v4f __attribute__((ext_vector_type(4)));
typedef unsigned int v2u __attribute__((ext_vector_type(2)));
typedef _Float16 f16x8 __attribute__((ext_vector_type(8)));
typedef float f32x4 __attribute__((ext_vector_type(4)));
typedef __fp16 hr2 __attribute__((ext_vector_type(2)));   // cvt_pkrtz native type

// conv geometry (round-15 proven core)
#define ZP 4
#define RGROWS 24
#define RCHUNK 66     // 8B chunks per region row (264 elems)
#define NCHK 7        // ceil(24*66/256)
#define ROWB 640      // LDS bytes per row (40 x 16B slots)
#define BUFB (25 * ROWB)

// ---------------------------------------------------------------------------
// One kernel, two block roles, pipelined at launch level:
//   launch k: blocks [0,nscan)   = scan of chunk k   (writes Rdst)
//             blocks [nscan,512) = conv of chunk k-1 (reads Rsrc, L3-hot)
// Roles are per-block -> barriers stay block-uniform. 9 launches cover T=128.
// ---------------------------------------------------------------------------
__global__ __launch_bounds__(256) void mega(
    const float* __restrict__ x, unsigned int* __restrict__ Rdst,
    const unsigned short* __restrict__ Rsrc, float* __restrict__ state,
    const float* __restrict__ wp, uint4* __restrict__ Bp,
    float* __restrict__ out, int scan_t0, int conv_t0, int nscan)
{
    __shared__ __align__(16) char lds[2 * BUFB];   // conv role only (32,000 B)
    const int tid = threadIdx.x;
    const int bid = blockIdx.x;

    if (bid < nscan) {
        // ================= scan role: 16-step double-EMA =================
        if (scan_t0 == 0 && bid < 2) {
            int idx = bid * 256 + tid;   // build B-matrix fragments once
            if (idx < 448) {
                int q = idx >> 6, l = idx & 63;
                int n = l & 15, g = l >> 4;
                unsigned int vs[8];
                #pragma unroll
                for (int j = 0; j < 8; ++j) {
                    int k = 32 * q + 8 * g + j;
                    int ky = k / 24, dc = k - ky * 24;
                    int kx = dc - n;
                    float wv = (ky < 9 && kx >= 0 && kx <= 8) ? wp[ky * 9 + kx] : 0.f;
                    _Float16 hv = (_Float16)wv;
                    vs[j] = (unsigned int)__builtin_bit_cast(unsigned short, hv);
                }
                uint4 pk;
                pk.x = vs[0] | (vs[1] << 16);
                pk.y = vs[2] | (vs[3] << 16);
                pk.z = vs[4] | (vs[5] << 16);
                pk.w = vs[6] | (vs[7] << 16);
                Bp[idx] = pk;
            }
        }

        const int gid = bid * 256 + tid;                 // 0 .. HW/4-1
        const v4f* xp = (const v4f*)x + (size_t)scan_t0 * (HW / 4) + gid;
        v2u* rp = (v2u*)Rdst + gid;
        v4f* st = (v4f*)state;

        v4f p, r;
        if (scan_t0 == 0) {
            p = (v4f)0.f; r = (v4f)0.f;
        } else {
            p = st[gid];
            r = st[HW / 4 + gid];
        }

#define SCAN_STEP(xv, t)                                                     \
    {                                                                        \
        hr2 h0 = __builtin_amdgcn_cvt_pkrtz(r.x, r.y);                       \
        hr2 h1 = __builtin_amdgcn_cvt_pkrtz(r.z, r.w);                       \
        v2u pk;                                                              \
        pk.x = __builtin_bit_cast(unsigned int, h0);                         \
        pk.y = __builtin_bit_cast(unsigned int, h1);                         \
        rp[(size_t)(t) * (HW / 4)] = pk;                                     \
        v4f rn = DECAY * r + p;                                              \
        p = DECAY * p + (xv);                                                \
        r = rn;                                                              \
    }

        #pragma unroll
        for (int b = 0; b < TC / 4; ++b) {
            v4f x0 = __builtin_nontemporal_load(&xp[(size_t)(4 * b + 0) * (HW / 4)]);
            v4f x1 = __builtin_nontemporal_load(&xp[(size_t)(4 * b + 1) * (HW / 4)]);
            v4f x2 = __builtin_nontemporal_load(&xp[(size_t)(4 * b + 2) * (HW / 4)]);
            v4f x3 = __builtin_nontemporal_load(&xp[(size_t)(4 * b + 3) * (HW / 4)]);
            SCAN_STEP(x0, 4 * b + 0); SCAN_STEP(x1, 4 * b + 1);
            SCAN_STEP(x2, 4 * b + 2); SCAN_STEP(x3, 4 * b + 3);
        }
#undef SCAN_STEP

        st[gid] = p;
        st[HW / 4 + gid] = r;
        return;
    }

    // ================= conv role: implicit-GEMM MFMA =================
    const int cb = bid - nscan;          // 0..255
    const int cz = cb >> 6;              // z-chunk 0..3 (ZP planes each)
    const int rem = cb & 63;
    const int bx = rem & 1, by = rem >> 1;
    const int l = tid & 63, wvi = tid >> 6;
    const int z0 = cz * ZP;
    const int X0 = bx * 256 - 4, Y0 = by * 16 - 4;
    const unsigned short* Rbase = Rsrc + (size_t)z0 * HW;

    f16x8 bf[7];
    #pragma unroll
    for (int q = 0; q < 7; ++q)
        bf[q] = __builtin_bit_cast(f16x8, Bp[q * 64 + l]);

    const int g = l >> 4, m = l & 15;
    int aoffb[7], ark[7], adq[7];
    #pragma unroll
    for (int q = 0; q < 7; ++q) {
        int k0 = 32 * q + 8 * g;
        int ky = k0 / 24, dc0 = k0 - 24 * ky;
        aoffb[q] = (m + ky) * ROWB;
        ark[q] = (m + ky) & 7;
        adq[q] = dc0 >> 3;
    }

    int goffk[NCHK], laddrk[NCHK];
    unsigned smask = 0;
    #pragma unroll
    for (int k = 0; k < NCHK; ++k) {
        int e = tid + 256 * k;
        int row = e / RCHUNK, c = e - row * RCHUNK;
        int gy = Y0 + row, gx = X0 + 4 * c;
        bool inr = (e < RGROWS * RCHUNK);
        bool inimg = inr && (unsigned)gy < H && (unsigned)gx < W;
        goffk[k] = gy * W + gx;
        laddrk[k] = row * ROWB + ((((c >> 1) ^ (row & 7))) << 4) + 8 * (c & 1);
        if (inr) smask |= (1u << k);
        if (inimg) smask |= (1u << (k + 16));
    }

    if (tid < 80) {   // zero K-pad row 24 in both buffers
        int b = tid / 40, s = tid - 40 * (tid / 40);
        uint4 z4 = make_uint4(0u, 0u, 0u, 0u);
        *(uint4*)(lds + b * BUFB + 24 * ROWB + 16 * s) = z4;
    }

#define LOADPLANE(pf, zz)                                                    \
    {                                                                        \
        const unsigned short* Rp_ = Rbase + (size_t)(zz) * HW;               \
        _Pragma("unroll")                                                    \
        for (int k = 0; k < NCHK; ++k)                                       \
            pf[k] = (smask >> (k + 16) & 1)                                  \
                        ? *(const uint2*)(Rp_ + goffk[k])                    \
                        : make_uint2(0u, 0u);                                \
    }

#define WRITEPLANE(boff, pf)                                                 \
    {                                                                        \
        _Pragma("unroll")                                                    \
        for (int k = 0; k < NCHK; ++k)                                       \
            if (smask >> k & 1)                                              \
                *(uint2*)(lds + (boff) + laddrk[k]) = pf[k];                 \
    }

    float* opb = out + (size_t)(conv_t0 + z0) * HW
                     + (size_t)(by * 16 + 4 * g) * W + bx * 256 + 64 * wvi + m;

#define COMPUTE(boff, zz)                                                    \
    {                                                                        \
        const char* buf = lds + (boff);                                      \
        _Pragma("unroll")                                                    \
        for (int n = 0; n < 4; ++n) {                                        \
            f32x4 acc = {0.f, 0.f, 0.f, 0.f};                                \
            _Pragma("unroll")                                                \
            for (int q = 0; q < 7; ++q) {                                    \
                int cso = (((8 * wvi + 2 * n + adq[q]) ^ ark[q]) << 4);      \
                f16x8 af = *(const f16x8*)(buf + aoffb[q] + cso);            \
                acc = __builtin_amdgcn_mfma_f32_16x16x32_f16(                \
                    af, bf[q], acc, 0, 0, 0);                                \
            }                                                                \
            float* op = opb + (size_t)(zz) * HW + 16 * n;                    \
            _Pragma("unroll")                                                \
            for (int i = 0; i < 4; ++i)                                      \
                __builtin_nontemporal_store(acc[i], op + (size_t)i * W);     \
        }                                                                    \
    }

    uint2 pfA[NCHK], pfB[NCHK];
    LOADPLANE(pfA, 0);
    LOADPLANE(pfB, 1);
    WRITEPLANE(0, pfA);
    __syncthreads();

    // ZP = 4 planes, fully static pipeline
    LOADPLANE(pfA, 2);
    COMPUTE(0, 0);
    WRITEPLANE(BUFB, pfB);
    __syncthreads();
    LOADPLANE(pfB, 3);
    COMPUTE(BUFB, 1);
    WRITEPLANE(0, pfA);
    __syncthreads();
    COMPUTE(0, 2);
    WRITEPLANE(BUFB, pfB);
    __syncthreads();
    COMPUTE(BUFB, 3);
#undef COMPUTE
#undef LOADPLANE
#undef WRITEPLANE
}

// ---------------------------------------------------------------------------
extern "C" void kernel_launch(void* const* d_in, const int* in_sizes, int n_in,
                              void* d_out, int out_size, void* d_ws, size_t ws_size,
                              hipStream_t stream) {
    const float* x = (const float*)d_in[0];  // [128,1,512,512]
    const float* w = (const float*)d_in[1];  // [1,1,9,9]
    float* out = (float*)d_out;              // [128,1,512,512]

    uint4* Bp = (uint4*)d_ws;                                   // 7168 B used
    float* state = (float*)((char*)d_ws + 8192);                // 2 fp32 planes
    unsigned short* RbufA = (unsigned short*)(state + 2 * (size_t)HW);
    unsigned short* RbufB = RbufA + (size_t)TC * HW;            // 8 MB each

    for (int k = 0; k <= NCHUNK; ++k) {
        int nscan = (k < NCHUNK) ? 256 : 0;
        int nconv = (k > 0) ? 256 : 0;
        unsigned short* Rdst = (k & 1) ? RbufB : RbufA;
        const unsigned short* Rsrc = (k & 1) ? RbufA : RbufB;
        mega<<<dim3(nscan + nconv), 256, 0, stream>>>(
            x, (unsigned int*)Rdst, Rsrc, state, w, Bp, out,
            k * TC, (k - 1) * TC, nscan);
    }
}

// Round 17
// 95.963 us; speedup vs baseline: 1.0706x; 1.0706x over previous
//
#include <hip/hip_runtime.h>

#define H 512
#define W 512
#define HW (H * W)
#define T 128
#define DECAY 0.8f

typedef float v4f __attribute__((ext_vector_type(4)));
typedef unsigned int v2u __attribute__((ext_vector_type(2)));
typedef _Float16 f16x8 __attribute__((ext_vector_type(8)));
typedef float f32x4 __attribute__((ext_vector_type(4)));
typedef __fp16 hr2 __attribute__((ext_vector_type(2)));   // cvt_pkrtz native type

// ---------------------------------------------------------------------------
// Pass A: pointwise double-EMA scan (~33 us total). R stored packed f16.
// Blocks 0..1 at t0==0 also build the conv B-matrix (224x16 f16) in MFMA
// fragment order: B[k=(ky,dc)][n] = w[ky][dc-n], lane l mfma q reads
// Bp[q*64+l] (8 f16).
// ---------------------------------------------------------------------------
__global__ __launch_bounds__(256) void scan_chunk(
    const float* __restrict__ x, unsigned int* __restrict__ Rbuf,
    float* __restrict__ state, const float* __restrict__ wp,
    uint4* __restrict__ Bp, int t0, int tc)
{
    if (t0 == 0 && blockIdx.x < 2) {
        int idx = blockIdx.x * 256 + threadIdx.x;   // 0..511
        if (idx < 448) {
            int q = idx >> 6, l = idx & 63;
            int n = l & 15, g = l >> 4;
            unsigned int vs[8];
            #pragma unroll
            for (int j = 0; j < 8; ++j) {
                int k = 32 * q + 8 * g + j;
                int ky = k / 24, dc = k - ky * 24;
                int kx = dc - n;
                float wv = (ky < 9 && kx >= 0 && kx <= 8) ? wp[ky * 9 + kx] : 0.f;
                _Float16 hv = (_Float16)wv;
                vs[j] = (unsigned int)__builtin_bit_cast(unsigned short, hv);
            }
            uint4 pk;
            pk.x = vs[0] | (vs[1] << 16);
            pk.y = vs[2] | (vs[3] << 16);
            pk.z = vs[4] | (vs[5] << 16);
            pk.w = vs[6] | (vs[7] << 16);
            Bp[idx] = pk;
        }
    }

    const int gid = blockIdx.x * 256 + threadIdx.x;      // 0 .. HW/4-1
    const v4f* xp = (const v4f*)x + (size_t)t0 * (HW / 4) + gid;
    v2u* rp = (v2u*)Rbuf + gid;                          // chunk-local base
    v4f* st = (v4f*)state;

    v4f p, r;
    if (t0 == 0) {
        p = (v4f)0.f; r = (v4f)0.f;
    } else {
        p = st[gid];
        r = st[HW / 4 + gid];
    }

#define SCAN_STEP(xv)                                                        \
    {                                                                        \
        hr2 h0 = __builtin_amdgcn_cvt_pkrtz(r.x, r.y);                       \
        hr2 h1 = __builtin_amdgcn_cvt_pkrtz(r.z, r.w);                       \
        v2u pk;                                                              \
        pk.x = __builtin_bit_cast(unsigned int, h0);                         \
        pk.y = __builtin_bit_cast(unsigned int, h1);                         \
        rp[(size_t)t * (HW / 4)] = pk;                                       \
        v4f rn = DECAY * r + p;                                              \
        p = DECAY * p + (xv);                                                \
        r = rn;                                                              \
        ++t;                                                                 \
    }

    int t = 0;
    const int t4 = tc & ~3;
    for (; t < t4;) {
        v4f x0 = __builtin_nontemporal_load(&xp[(size_t)(t + 0) * (HW / 4)]);
        v4f x1 = __builtin_nontemporal_load(&xp[(size_t)(t + 1) * (HW / 4)]);
        v4f x2 = __builtin_nontemporal_load(&xp[(size_t)(t + 2) * (HW / 4)]);
        v4f x3 = __builtin_nontemporal_load(&xp[(size_t)(t + 3) * (HW / 4)]);
        SCAN_STEP(x0); SCAN_STEP(x1); SCAN_STEP(x2); SCAN_STEP(x3);
    }
    for (; t < tc;) {
        v4f xv = __builtin_nontemporal_load(&xp[(size_t)t * (HW / 4)]);
        SCAN_STEP(xv);
    }
#undef SCAN_STEP

    st[gid] = p;
    st[HW / 4 + gid] = r;
}

// ---------------------------------------------------------------------------
// Pass B: 9x9 conv as implicit GEMM (round-15 proven core, unchanged).
// Block = 256w x 16h tile, shared 24-row region, coalesced 8B-chunk staging,
// XOR-swizzled 640B-stride LDS rows (conflict-free b128 A-reads), per wave 4
// 16x16 tiles: 7 ds_read_b128 + 7 mfma_f32_16x16x32_f16 each. Dbuf LDS +
// 2-deep register prefetch + 1 barrier/plane, ZP=4 planes per block.
// ---------------------------------------------------------------------------
#define ZP 4
#define RGROWS 24
#define RCHUNK 66     // 8B chunks per region row (264 elems)
#define NCHK 7        // ceil(24*66/256)
#define ROWB 640      // LDS bytes per row (40 x 16B slots)
#define BUFB (25 * ROWB)

__global__ __launch_bounds__(256) void conv_mfma(
    const unsigned short* __restrict__ Rbuf, const uint4* __restrict__ Bp,
    float* __restrict__ out, int t0, int tc)
{
    __shared__ __align__(16) char lds[2 * BUFB];   // 32,000 B

    const int tid = threadIdx.x;
    const int l = tid & 63, wvi = tid >> 6;
    const int bx = blockIdx.x, by = blockIdx.y;
    const int z0 = blockIdx.z * ZP;
    const int zc = (tc - z0 < ZP) ? (tc - z0) : ZP;
    const int X0 = bx * 256 - 4, Y0 = by * 16 - 4;
    const unsigned short* Rbase = Rbuf + (size_t)z0 * HW;

    f16x8 bf[7];
    #pragma unroll
    for (int q = 0; q < 7; ++q)
        bf[q] = __builtin_bit_cast(f16x8, Bp[q * 64 + l]);

    const int g = l >> 4, m = l & 15;
    int aoffb[7], ark[7], adq[7];
    #pragma unroll
    for (int q = 0; q < 7; ++q) {
        int k0 = 32 * q + 8 * g;
        int ky = k0 / 24, dc0 = k0 - 24 * ky;
        aoffb[q] = (m + ky) * ROWB;
        ark[q] = (m + ky) & 7;
        adq[q] = dc0 >> 3;          // 0,1,2
    }

    int goffk[NCHK], laddrk[NCHK];
    unsigned smask = 0;
    #pragma unroll
    for (int k = 0; k < NCHK; ++k) {
        int e = tid + 256 * k;
        int row = e / RCHUNK, c = e - row * RCHUNK;
        int gy = Y0 + row, gx = X0 + 4 * c;
        bool inr = (e < RGROWS * RCHUNK);
        bool inimg = inr && (unsigned)gy < H && (unsigned)gx < W;
        goffk[k] = gy * W + gx;
        laddrk[k] = row * ROWB + ((((c >> 1) ^ (row & 7))) << 4) + 8 * (c & 1);
        if (inr) smask |= (1u << k);
        if (inimg) smask |= (1u << (k + 16));
    }

    // zero K-pad row 24 in both buffers (k>=216 zero-weight taps read it)
    if (tid < 80) {
        int b = tid / 40, s = tid - 40 * (tid / 40);
        uint4 z4 = make_uint4(0u, 0u, 0u, 0u);
        *(uint4*)(lds + b * BUFB + 24 * ROWB + 16 * s) = z4;
    }

#define LOADPLANE(pf, zz)                                                    \
    {                                                                        \
        const unsigned short* Rp_ = Rbase + (size_t)(zz) * HW;               \
        _Pragma("unroll")                                                    \
        for (int k = 0; k < NCHK; ++k)                                       \
            pf[k] = (smask >> (k + 16) & 1)                                  \
                        ? *(const uint2*)(Rp_ + goffk[k])                    \
                        : make_uint2(0u, 0u);                                \
    }

#define WRITEPLANE(boff, pf)                                                 \
    {                                                                        \
        _Pragma("unroll")                                                    \
        for (int k = 0; k < NCHK; ++k)                                       \
            if (smask >> k & 1)                                              \
                *(uint2*)(lds + (boff) + laddrk[k]) = pf[k];                 \
    }

    float* opb = out + (size_t)(t0 + z0) * HW
                     + (size_t)(by * 16 + 4 * g) * W + bx * 256 + 64 * wvi + m;

#define COMPUTE(boff, zz)                                                    \
    {                                                                        \
        const char* buf = lds + (boff);                                      \
        _Pragma("unroll")                                                    \
        for (int n = 0; n < 4; ++n) {                                        \
            f32x4 acc = {0.f, 0.f, 0.f, 0.f};                                \
            _Pragma("unroll")                                                \
            for (int q = 0; q < 7; ++q) {                                    \
                int cso = (((8 * wvi + 2 * n + adq[q]) ^ ark[q]) << 4);      \
                f16x8 af = *(const f16x8*)(buf + aoffb[q] + cso);            \
                acc = __builtin_amdgcn_mfma_f32_16x16x32_f16(                \
                    af, bf[q], acc, 0, 0, 0);                                \
            }                                                                \
            float* op = opb + (size_t)(zz) * HW + 16 * n;                    \
            _Pragma("unroll")                                                \
            for (int i = 0; i < 4; ++i)                                      \
                __builtin_nontemporal_store(acc[i], op + (size_t)i * W);     \
        }                                                                    \
    }

    uint2 pfA[NCHK], pfB[NCHK];
    LOADPLANE(pfA, 0);
    if (zc > 1) LOADPLANE(pfB, 1);
    WRITEPLANE(0, pfA);
    __syncthreads();

    for (int zz = 0; zz < zc; zz += 2) {
        if (zz + 2 < zc) LOADPLANE(pfA, zz + 2);   // issue 2 phases early
        COMPUTE(0, zz);
        if (zz + 1 < zc) {
            WRITEPLANE(BUFB, pfB);                 // waits pfB (long cover)
            __syncthreads();
            if (zz + 3 < zc) LOADPLANE(pfB, zz + 3);
            COMPUTE(BUFB, zz + 1);
            if (zz + 2 < zc) {
                WRITEPLANE(0, pfA);
                __syncthreads();
            }
        }
    }
#undef COMPUTE
#undef LOADPLANE
#undef WRITEPLANE
}

// ---------------------------------------------------------------------------
extern "C" void kernel_launch(void* const* d_in, const int* in_sizes, int n_in,
                              void* d_out, int out_size, void* d_ws, size_t ws_size,
                              hipStream_t stream) {
    const float* x = (const float*)d_in[0];  // [128,1,512,512]
    const float* w = (const float*)d_in[1];  // [1,1,9,9]
    float* out = (float*)d_out;              // [128,1,512,512]

    uint4* Bp = (uint4*)d_ws;                                  // 7168 B used
    float* state = (float*)((char*)d_ws + 8192);               // 2 fp32 planes
    unsigned short* Rbuf = (unsigned short*)(state + 2 * (size_t)HW);

    size_t head_b = 8192 + 2 * (size_t)HW * sizeof(float);
    size_t plane_b = (size_t)HW * sizeof(unsigned short);
    int maxTc = 1;
    if (ws_size > head_b + plane_b)
        maxTc = (int)((ws_size - head_b) / plane_b);
    // Tc=64: R chunk (33.5 MB) stays L3-resident between the scan launch that
    // writes it and the conv launch that reads it (round-16 lesson: at Tc=128
    // the x/out streams evict R -> conv stage loads eat HBM latency).
    int Tc = 64;
    if (Tc > maxTc) Tc = maxTc;
    if (Tc < 1) Tc = 1;

    for (int t0 = 0; t0 < T; t0 += Tc) {
        int tc = T - t0;
        if (tc > Tc) tc = Tc;
        scan_chunk<<<dim3(HW / 1024), 256, 0, stream>>>(
            x, (unsigned int*)Rbuf, state, w, Bp, t0, tc);
        conv_mfma<<<dim3(W / 256, H / 16, (tc + ZP - 1) / ZP), 256, 0, stream>>>(
            Rbuf, Bp, out, t0, tc);
    }
}

// Round 18
// 90.136 us; speedup vs baseline: 1.1398x; 1.0646x over previous
//
#include <hip/hip_runtime.h>

#define H 512
#define W 512
#define HW (H * W)
#define T 128
#define DECAY 0.8f

typedef float v4f __attribute__((ext_vector_type(4)));
typedef unsigned int v2u __attribute__((ext_vector_type(2)));
typedef _Float16 f16x8 __attribute__((ext_vector_type(8)));
typedef float f32x4 __attribute__((ext_vector_type(4)));
typedef __fp16 hr2 __attribute__((ext_vector_type(2)));   // cvt_pkrtz native type

// ---------------------------------------------------------------------------
// Pass A: pointwise double-EMA scan (~33 us, ~6.1 TB/s = stream roofline).
// R stored packed f16. Blocks 0..1 at t0==0 also build the conv B-matrix
// (224x16 f16) in MFMA fragment order: B[k=(ky,dc)][n] = w[ky][dc-n].
// ---------------------------------------------------------------------------
__global__ __launch_bounds__(256) void scan_chunk(
    const float* __restrict__ x, unsigned int* __restrict__ Rbuf,
    float* __restrict__ state, const float* __restrict__ wp,
    uint4* __restrict__ Bp, int t0, int tc)
{
    if (t0 == 0 && blockIdx.x < 2) {
        int idx = blockIdx.x * 256 + threadIdx.x;   // 0..511
        if (idx < 448) {
            int q = idx >> 6, l = idx & 63;
            int n = l & 15, g = l >> 4;
            unsigned int vs[8];
            #pragma unroll
            for (int j = 0; j < 8; ++j) {
                int k = 32 * q + 8 * g + j;
                int ky = k / 24, dc = k - ky * 24;
                int kx = dc - n;
                float wv = (ky < 9 && kx >= 0 && kx <= 8) ? wp[ky * 9 + kx] : 0.f;
                _Float16 hv = (_Float16)wv;
                vs[j] = (unsigned int)__builtin_bit_cast(unsigned short, hv);
            }
            uint4 pk;
            pk.x = vs[0] | (vs[1] << 16);
            pk.y = vs[2] | (vs[3] << 16);
            pk.z = vs[4] | (vs[5] << 16);
            pk.w = vs[6] | (vs[7] << 16);
            Bp[idx] = pk;
        }
    }

    const int gid = blockIdx.x * 256 + threadIdx.x;      // 0 .. HW/4-1
    const v4f* xp = (const v4f*)x + (size_t)t0 * (HW / 4) + gid;
    v2u* rp = (v2u*)Rbuf + gid;
    v4f* st = (v4f*)state;

    v4f p, r;
    if (t0 == 0) {
        p = (v4f)0.f; r = (v4f)0.f;
    } else {
        p = st[gid];
        r = st[HW / 4 + gid];
    }

#define SCAN_STEP(xv)                                                        \
    {                                                                        \
        hr2 h0 = __builtin_amdgcn_cvt_pkrtz(r.x, r.y);                       \
        hr2 h1 = __builtin_amdgcn_cvt_pkrtz(r.z, r.w);                       \
        v2u pk;                                                              \
        pk.x = __builtin_bit_cast(unsigned int, h0);                         \
        pk.y = __builtin_bit_cast(unsigned int, h1);                         \
        rp[(size_t)t * (HW / 4)] = pk;                                       \
        v4f rn = DECAY * r + p;                                              \
        p = DECAY * p + (xv);                                                \
        r = rn;                                                              \
        ++t;                                                                 \
    }

    int t = 0;
    const int t4 = tc & ~3;
    for (; t < t4;) {
        v4f x0 = __builtin_nontemporal_load(&xp[(size_t)(t + 0) * (HW / 4)]);
        v4f x1 = __builtin_nontemporal_load(&xp[(size_t)(t + 1) * (HW / 4)]);
        v4f x2 = __builtin_nontemporal_load(&xp[(size_t)(t + 2) * (HW / 4)]);
        v4f x3 = __builtin_nontemporal_load(&xp[(size_t)(t + 3) * (HW / 4)]);
        SCAN_STEP(x0); SCAN_STEP(x1); SCAN_STEP(x2); SCAN_STEP(x3);
    }
    for (; t < tc;) {
        v4f xv = __builtin_nontemporal_load(&xp[(size_t)t * (HW / 4)]);
        SCAN_STEP(xv);
    }
#undef SCAN_STEP

    st[gid] = p;
    st[HW / 4 + gid] = r;
}

// ---------------------------------------------------------------------------
// Pass B: 9x9 conv as implicit GEMM (round-15 proven core).
// Block = 256w x 16h tile, shared 24-row region, coalesced 8B-chunk staging,
// XOR-swizzled 640B-stride LDS rows (conflict-free b128 A-reads), per wave 4
// 16x16 tiles: 7 ds_read_b128 + 7 mfma_f32_16x16x32_f16 each. Dbuf LDS +
// 2-deep register prefetch + 1 barrier/plane, ZP=4 planes per block.
// ---------------------------------------------------------------------------
#define ZP 4
#define RGROWS 24
#define RCHUNK 66     // 8B chunks per region row (264 elems)
#define NCHK 7        // ceil(24*66/256)
#define ROWB 640      // LDS bytes per row (40 x 16B slots)
#define BUFB (25 * ROWB)

__global__ __launch_bounds__(256) void conv_mfma(
    const unsigned short* __restrict__ Rbuf, const uint4* __restrict__ Bp,
    float* __restrict__ out, int t0, int tc)
{
    __shared__ __align__(16) char lds[2 * BUFB];   // 32,000 B

    const int tid = threadIdx.x;
    const int l = tid & 63, wvi = tid >> 6;
    const int bx = blockIdx.x, by = blockIdx.y;
    const int z0 = blockIdx.z * ZP;
    const int zc = (tc - z0 < ZP) ? (tc - z0) : ZP;
    const int X0 = bx * 256 - 4, Y0 = by * 16 - 4;
    const unsigned short* Rbase = Rbuf + (size_t)z0 * HW;

    f16x8 bf[7];
    #pragma unroll
    for (int q = 0; q < 7; ++q)
        bf[q] = __builtin_bit_cast(f16x8, Bp[q * 64 + l]);

    const int g = l >> 4, m = l & 15;
    int aoffb[7], ark[7], adq[7];
    #pragma unroll
    for (int q = 0; q < 7; ++q) {
        int k0 = 32 * q + 8 * g;
        int ky = k0 / 24, dc0 = k0 - 24 * ky;
        aoffb[q] = (m + ky) * ROWB;
        ark[q] = (m + ky) & 7;
        adq[q] = dc0 >> 3;          // 0,1,2
    }

    int goffk[NCHK], laddrk[NCHK];
    unsigned smask = 0;
    #pragma unroll
    for (int k = 0; k < NCHK; ++k) {
        int e = tid + 256 * k;
        int row = e / RCHUNK, c = e - row * RCHUNK;
        int gy = Y0 + row, gx = X0 + 4 * c;
        bool inr = (e < RGROWS * RCHUNK);
        bool inimg = inr && (unsigned)gy < H && (unsigned)gx < W;
        goffk[k] = gy * W + gx;
        laddrk[k] = row * ROWB + ((((c >> 1) ^ (row & 7))) << 4) + 8 * (c & 1);
        if (inr) smask |= (1u << k);
        if (inimg) smask |= (1u << (k + 16));
    }

    // zero K-pad row 24 in both buffers (k>=216 zero-weight taps read it)
    if (tid < 80) {
        int b = tid / 40, s = tid - 40 * (tid / 40);
        uint4 z4 = make_uint4(0u, 0u, 0u, 0u);
        *(uint4*)(lds + b * BUFB + 24 * ROWB + 16 * s) = z4;
    }

#define LOADPLANE(pf, zz)                                                    \
    {                                                                        \
        const unsigned short* Rp_ = Rbase + (size_t)(zz) * HW;               \
        _Pragma("unroll")                                                    \
        for (int k = 0; k < NCHK; ++k)                                       \
            pf[k] = (smask >> (k + 16) & 1)                                  \
                        ? *(const uint2*)(Rp_ + goffk[k])                    \
                        : make_uint2(0u, 0u);                                \
    }

#define WRITEPLANE(boff, pf)                                                 \
    {                                                                        \
        _Pragma("unroll")                                                    \
        for (int k = 0; k < NCHK; ++k)                                       \
            if (smask >> k & 1)                                              \
                *(uint2*)(lds + (boff) + laddrk[k]) = pf[k];                 \
    }

    float* opb = out + (size_t)(t0 + z0) * HW
                     + (size_t)(by * 16 + 4 * g) * W + bx * 256 + 64 * wvi + m;

#define COMPUTE(boff, zz)                                                    \
    {                                                                        \
        const char* buf = lds + (boff);                                      \
        _Pragma("unroll")                                                    \
        for (int n = 0; n < 4; ++n) {                                        \
            f32x4 acc = {0.f, 0.f, 0.f, 0.f};                                \
            _Pragma("unroll")                                                \
            for (int q = 0; q < 7; ++q) {                                    \
                int cso = (((8 * wvi + 2 * n + adq[q]) ^ ark[q]) << 4);      \
                f16x8 af = *(const f16x8*)(buf + aoffb[q] + cso);            \
                acc = __builtin_amdgcn_mfma_f32_16x16x32_f16(                \
                    af, bf[q], acc, 0, 0, 0);                                \
            }                                                                \
            float* op = opb + (size_t)(zz) * HW + 16 * n;                    \
            _Pragma("unroll")                                                \
            for (int i = 0; i < 4; ++i)                                      \
                __builtin_nontemporal_store(acc[i], op + (size_t)i * W);     \
        }                                                                    \
    }

    uint2 pfA[NCHK], pfB[NCHK];
    LOADPLANE(pfA, 0);
    if (zc > 1) LOADPLANE(pfB, 1);
    WRITEPLANE(0, pfA);
    __syncthreads();

    for (int zz = 0; zz < zc; zz += 2) {
        if (zz + 2 < zc) LOADPLANE(pfA, zz + 2);   // issue 2 phases early
        COMPUTE(0, zz);
        if (zz + 1 < zc) {
            WRITEPLANE(BUFB, pfB);                 // waits pfB (long cover)
            __syncthreads();
            if (zz + 3 < zc) LOADPLANE(pfB, zz + 3);
            COMPUTE(BUFB, zz + 1);
            if (zz + 2 < zc) {
                WRITEPLANE(0, pfA);
                __syncthreads();
            }
        }
    }
#undef COMPUTE
#undef LOADPLANE
#undef WRITEPLANE
}

// ---------------------------------------------------------------------------
extern "C" void kernel_launch(void* const* d_in, const int* in_sizes, int n_in,
                              void* d_out, int out_size, void* d_ws, size_t ws_size,
                              hipStream_t stream) {
    const float* x = (const float*)d_in[0];  // [128,1,512,512]
    const float* w = (const float*)d_in[1];  // [1,1,9,9]
    float* out = (float*)d_out;              // [128,1,512,512]

    uint4* Bp = (uint4*)d_ws;                                  // 7168 B used
    float* state = (float*)((char*)d_ws + 8192);               // 2 fp32 planes
    unsigned short* Rbuf = (unsigned short*)(state + 2 * (size_t)HW);

    size_t head_b = 8192 + 2 * (size_t)HW * sizeof(float);
    size_t plane_b = (size_t)HW * sizeof(unsigned short);
    int maxTc = 1;
    if (ws_size > head_b + plane_b)
        maxTc = (int)((ws_size - head_b) / plane_b);
    // Tc=128 (full) measured best: Tc=64 chunking regressed (round 17,
    // +6 us launch tails), launch-level role fusion regressed (round 16).
    int Tc = T;
    if (Tc > maxTc) Tc = maxTc;
    if (Tc < 1) Tc = 1;

    for (int t0 = 0; t0 < T; t0 += Tc) {
        int tc = T - t0;
        if (tc > Tc) tc = Tc;
        scan_chunk<<<dim3(HW / 1024), 256, 0, stream>>>(
            x, (unsigned int*)Rbuf, state, w, Bp, t0, tc);
        conv_mfma<<<dim3(W / 256, H / 16, (tc + ZP - 1) / ZP), 256, 0, stream>>>(
            Rbuf, Bp, out, t0, tc);
    }
}